// Round 9
// baseline (293.607 us; speedup 1.0000x reference)
//
#include <hip/hip_runtime.h>

using bf16   = __bf16;
using bf16x8 = __attribute__((ext_vector_type(8))) __bf16;
using f32x4  = __attribute__((ext_vector_type(4))) float;
using u32x4  = __attribute__((ext_vector_type(4))) unsigned;

// B=2 T=2048 D=2048 H=32 KVH=8 HD=64 GROUPS=4 ; M=B*T=4096 ; NQKV=3072
#define T_SEQ 2048
#define NQKV 3072

__device__ __forceinline__ void async_cp16(const bf16* g, bf16* l) {
  __builtin_amdgcn_global_load_lds((__attribute__((address_space(1))) void*)(void*)g,
                                   (__attribute__((address_space(3))) void*)l, 16, 0, 0);
}

// ------------- fused prep: cvt(x) | wq^T | wkv^T | wo^T as z-slices -------------
__global__ __launch_bounds__(256) void prep_kernel(
    const float* __restrict__ x, bf16* __restrict__ xbf,
    const float* __restrict__ wq, const float* __restrict__ wkv,
    const float* __restrict__ wo, bf16* __restrict__ w1,
    bf16* __restrict__ woT) {
  const int z = blockIdx.z;
  if (z == 0) {                 // fp32 -> bf16 convert of x (64x64 blocks = 4096)
    long i = (((long)blockIdx.y * 64 + blockIdx.x) * 256 + threadIdx.x) * 8;
    float4 a = *(const float4*)(x + i);
    float4 c = *(const float4*)(x + i + 4);
    bf16x8 v;
    v[0] = (bf16)a.x; v[1] = (bf16)a.y; v[2] = (bf16)a.z; v[3] = (bf16)a.w;
    v[4] = (bf16)c.x; v[5] = (bf16)c.y; v[6] = (bf16)c.z; v[7] = (bf16)c.w;
    *(bf16x8*)(xbf + i) = v;
    return;
  }
  const float* in; bf16* out; int R, C;
  if (z == 1)      { in = wq;  out = w1;                R = 2048; C = 2048; }
  else if (z == 2) { if (blockIdx.x >= 32) return;
                     in = wkv; out = w1 + 2048L * 2048; R = 2048; C = 1024; }
  else             { in = wo;  out = woT;               R = 2048; C = 2048; }
  __shared__ float tile[32][33];
  const int tc = blockIdx.x * 32;
  const int tr = blockIdx.y * 32;
  const int t = threadIdx.x;
  const int lr = t >> 5;
  const int lc = t & 31;
#pragma unroll
  for (int i = 0; i < 4; ++i)
    tile[lr + i * 8][lc] = in[(size_t)(tr + lr + i * 8) * C + tc + lc];
  __syncthreads();
#pragma unroll
  for (int i = 0; i < 4; ++i)
    out[(size_t)(tc + lr + i * 8) * R + tr + lc] = (bf16)tile[lc][lr + i * 8];
}

// ------------- transpose + convert (standalone, fallback paths) ----------------
__global__ __launch_bounds__(256) void transpose_cvt(const float* __restrict__ in,
                                                     bf16* __restrict__ out,
                                                     int R, int C) {
  __shared__ float tile[32][33];
  const int tc = blockIdx.x * 32;
  const int tr = blockIdx.y * 32;
  const int t = threadIdx.x;
  const int lr = t >> 5;
  const int lc = t & 31;
#pragma unroll
  for (int i = 0; i < 4; ++i)
    tile[lr + i * 8][lc] = in[(size_t)(tr + lr + i * 8) * C + tc + lc];
  __syncthreads();
#pragma unroll
  for (int i = 0; i < 4; ++i)
    out[(size_t)(tc + lr + i * 8) * R + tr + lc] = (bf16)tile[lc][lr + i * 8];
}

// ------------- bf16 transpose of the V block of qkv (fallback path) -------------
__global__ __launch_bounds__(256) void transpose_v(const bf16* __restrict__ in,
                                                   bf16* __restrict__ out) {
  __shared__ bf16 tile[32][33];
  const int c0 = blockIdx.x * 32;   // 0..480
  const int r0 = blockIdx.y * 32;   // 0..4064
  const int t = threadIdx.x;
  const int lr = t >> 5;
  const int lc = t & 31;
#pragma unroll
  for (int i = 0; i < 4; ++i)
    tile[lr + i * 8][lc] = in[(size_t)(r0 + lr + i * 8) * NQKV + 2560 + c0 + lc];
  __syncthreads();
#pragma unroll
  for (int i = 0; i < 4; ++i) {
    int c = c0 + lr + i * 8;
    int r = r0 + lc;
    out[(size_t)((r >> 11) * 512 + c) * 2048 + (r & 2047)] = tile[lc][lr + i * 8];
  }
}

// ------------- GEMM: C[M][N] = A[M][K] * Bt[N][K]^T  (bf16 in, fp32 acc) --------
// (unchanged from r15/r8: m97 structure + V_SPLIT epilogue. (256,4) measured
// neutral - grid 768 = 3/CU exactly, cap never binds; V_SPLIT scatter costs
// ~4us on gemm1 but deletes transpose_v (~4.5us) - net wash, fewer launches.)
template <bool OUT_BF16, bool V_SPLIT>
__global__ __launch_bounds__(256, 4)
void gemm_kernel(const bf16* __restrict__ A, const bf16* __restrict__ Bt,
                 void* __restrict__ Cout, bf16* __restrict__ vTout,
                 int Kdim, int Ndim) {
  __shared__ __attribute__((aligned(16))) bf16 As[128 * 64];
  __shared__ __attribute__((aligned(16))) bf16 Bs[128 * 64];
  const int tid  = threadIdx.x;
  const int lane = tid & 63;
  const int wave = tid >> 6;
  const int l16  = lane & 15;
  const int q4   = lane >> 4;
  const long m0 = (long)blockIdx.y * 128;
  const long n0 = (long)blockIdx.x * 128;
  const int wm = (wave >> 1) * 64;
  const int wn = (wave & 1) * 64;

  f32x4 acc[4][4] = {};

  for (int k0 = 0; k0 < Kdim; k0 += 64) {
    __syncthreads();
#pragma unroll
    for (int rr = 0; rr < 4; ++rr) {
      int ci  = rr * 256 + tid;     // 16B chunk index 0..1023
      int row = ci >> 3;
      int chp = ci & 7;             // swizzled LDS chunk slot
      int ch  = chp ^ (row & 7);    // global chunk
      async_cp16(A + (m0 + row) * (long)Kdim + k0 + ch * 8, &As[ci * 8]);
      async_cp16(Bt + (n0 + row) * (long)Kdim + k0 + ch * 8, &Bs[ci * 8]);
    }
    __syncthreads();
#pragma unroll
    for (int ks = 0; ks < 2; ++ks) {
      bf16x8 af[4], bfr[4];
#pragma unroll
      for (int mt = 0; mt < 4; ++mt) {
        int row = wm + mt * 16 + l16;
        int chp = (ks * 4 + q4) ^ (row & 7);
        af[mt] = *(const bf16x8*)&As[row * 64 + chp * 8];
      }
#pragma unroll
      for (int nt = 0; nt < 4; ++nt) {
        int row = wn + nt * 16 + l16;
        int chp = (ks * 4 + q4) ^ (row & 7);
        bfr[nt] = *(const bf16x8*)&Bs[row * 64 + chp * 8];
      }
#pragma unroll
      for (int mt = 0; mt < 4; ++mt)
#pragma unroll
        for (int nt = 0; nt < 4; ++nt)
          acc[mt][nt] = __builtin_amdgcn_mfma_f32_16x16x32_bf16(af[mt], bfr[nt],
                                                                acc[mt][nt], 0, 0, 0);
    }
  }

  if constexpr (V_SPLIT) {
    if (n0 >= 2560) {   // V block: write transposed directly to vT
#pragma unroll
      for (int mt = 0; mt < 4; ++mt)
#pragma unroll
        for (int nt = 0; nt < 4; ++nt)
#pragma unroll
          for (int r = 0; r < 4; ++r) {
            long row = m0 + wm + mt * 16 + q4 * 4 + r;
            long c   = n0 + wn + nt * 16 + l16 - 2560;
            vTout[((row >> 11) * 512 + c) * 2048 + (row & 2047)] =
                (bf16)acc[mt][nt][r];
          }
      return;
    }
  }
#pragma unroll
  for (int mt = 0; mt < 4; ++mt)
#pragma unroll
    for (int nt = 0; nt < 4; ++nt)
#pragma unroll
      for (int r = 0; r < 4; ++r) {
        long row = m0 + wm + mt * 16 + q4 * 4 + r;
        long col = n0 + wn + nt * 16 + l16;
        float v = acc[mt][nt][r];
        if constexpr (OUT_BF16)
          ((bf16*)Cout)[row * Ndim + col] = (bf16)v;
        else
          ((float*)Cout)[row * Ndim + col] = v;
      }
}

// ------------- causal GQA flash attention ---------------------------------------
// r16: KVBLK 64 -> 128. Per-64kv the old loop paid 2 barriers + an LDS write
// round + fragment re-reads for only ~36 MFMA (MfmaUtil ~33%); staging both
// 64-halves per barrier pair halves that overhead (same amortization lever as
// the gemm 64->128 tile step). Compute body is the verified r14 body run twice
// (per half) against Ks[half]/Vs[half]. T14 prefetch regs double: kr[4]/vr[4]
// (+32 VGPR, ~150 peak; fits the (256,3) cap ~170. WRITE_SIZE = spill tripwire).
// LDS 32 KB -> 3 blocks/CU unchanged.
__global__ __launch_bounds__(256, 3)
void attn_kernel(const bf16* __restrict__ qkv, const bf16* __restrict__ vT,
                 bf16* __restrict__ outb) {
  __shared__ __attribute__((aligned(16))) bf16 Ks[2][64 * 64];
  __shared__ __attribute__((aligned(16))) bf16 Vs[2][64 * 64];

  const int tid  = threadIdx.x;
  const int lane = tid & 63;
  const int wave = tid >> 6;
  const int l16  = lane & 15;
  const int q4   = lane >> 4;

  const int bid = blockIdx.x;
  const int qt  = 15 - (bid >> 6);   // heavy q-tiles dispatched first
  const int bh  = bid & 63;
  const int b   = bh >> 5;
  const int h   = bh & 31;
  const int kvh = h >> 2;
  const long rowbase = (long)b * T_SEQ;

  const int qrow0 = qt * 128;
  const int wq0   = qrow0 + wave * 32;
  const float cexp = 0.125f * 1.4426950408889634f;  // scale * log2(e), folded into Q

  // Q fragments in registers, pre-scaled by cexp (so P = exp2(S) directly)
  bf16x8 aq[2][2];
#pragma unroll
  for (int mt = 0; mt < 2; ++mt)
#pragma unroll
    for (int ks = 0; ks < 2; ++ks) {
      bf16x8 v = *(const bf16x8*)(qkv +
          (rowbase + wq0 + mt * 16 + l16) * (long)NQKV + h * 64 + ks * 32 + q4 * 8);
#pragma unroll
      for (int i = 0; i < 8; ++i) v[i] = (bf16)((float)v[i] * cexp);
      aq[mt][ks] = v;
    }

  // ones B-fragment: B[k][n=0]=1 -> accumulates row-sums of P into col 0
  bf16x8 ones_f;
#pragma unroll
  for (int i = 0; i < 8; ++i) ones_f[i] = (l16 == 0) ? (bf16)1.0f : (bf16)0.0f;

  f32x4 o[2][4] = {};
  f32x4 o_l[2] = {};

  const bf16* kbase = qkv + rowbase * (long)NQKV + 2048 + kvh * 64;
  const bf16* vbase = vT + ((long)b * 512 + kvh * 64) * 2048;

  const int ntiles = qt + 1;   // 128-wide kv tiles; coverage = (qt+1)*128 exactly

  // T14 prologue: tile 0 (kv rows 0..127) -> regs
  bf16x8 kr[4], vr[4];
#pragma unroll
  for (int h2 = 0; h2 < 4; ++h2) {
    int ci = h2 * 256 + tid;          // 0..1023
    int half = ci >> 9, cin = ci & 511;
    int row = cin >> 3, ch = (cin & 7) ^ (row & 7);
    kr[h2] = *(const bf16x8*)(kbase + (long)(half * 64 + row) * NQKV + ch * 8);
    vr[h2] = *(const bf16x8*)(vbase + (long)row * 2048 + half * 64 + ch * 8);
  }

  for (int t = 0; t < ntiles; ++t) {
    const int j0 = t * 128;
    __syncthreads();                     // all waves done reading prev tile's LDS
#pragma unroll
    for (int h2 = 0; h2 < 4; ++h2) {     // regs -> LDS
      int ci = h2 * 256 + tid;
      int half = ci >> 9, cin = ci & 511;
      *(bf16x8*)&Ks[half][cin * 8] = kr[h2];
      *(bf16x8*)&Vs[half][cin * 8] = vr[h2];
    }
    __syncthreads();                     // LDS ready
    if (t + 1 < ntiles) {                // issue next tile's loads; land during compute
      const int jn = j0 + 128;
#pragma unroll
      for (int h2 = 0; h2 < 4; ++h2) {
        int ci = h2 * 256 + tid;
        int half = ci >> 9, cin = ci & 511;
        int row = cin >> 3, ch = (cin & 7) ^ (row & 7);
        kr[h2] = *(const bf16x8*)(kbase + (long)(jn + half * 64 + row) * NQKV + ch * 8);
        vr[h2] = *(const bf16x8*)(vbase + (long)row * 2048 + jn + half * 64 + ch * 8);
      }
    }

#pragma unroll
    for (int half = 0; half < 2; ++half) {
      const int j0h = j0 + half * 64;
      if (j0h > wq0 + 31) continue;   // 64-half entirely above diagonal

      // S^T = K Q^T  (operand-swapped: tiles [kv = nt][q = mt])
      f32x4 s[2][4] = {};
#pragma unroll
      for (int ks = 0; ks < 2; ++ks) {
        bf16x8 bk[4];
#pragma unroll
        for (int nt = 0; nt < 4; ++nt) {
          int row  = nt * 16 + l16;
          int slot = (ks * 4 + q4) ^ (row & 7);
          bk[nt] = *(const bf16x8*)&Ks[half][row * 64 + slot * 8];
        }
#pragma unroll
        for (int mt = 0; mt < 2; ++mt)
#pragma unroll
          for (int nt = 0; nt < 4; ++nt)
            s[mt][nt] = __builtin_amdgcn_mfma_f32_16x16x32_bf16(bk[nt], aq[mt][ks],
                                                                s[mt][nt], 0, 0, 0);
      }

      if (j0h + 63 > wq0) {   // diagonal tile: causal mask (S^T: row=kv, col=q)
#pragma unroll
        for (int mt = 0; mt < 2; ++mt)
#pragma unroll
          for (int nt = 0; nt < 4; ++nt)
#pragma unroll
            for (int r = 0; r < 4; ++r) {
              int rg = wq0 + mt * 16 + l16;          // q row
              int cg = j0h + nt * 16 + q4 * 4 + r;   // kv col
              if (cg > rg) s[mt][nt][r] = -__builtin_inff();
            }
      }

      // P = exp2(S^T) via bare v_exp_f32; pack pairs with v_cvt_pk_bf16_f32;
      // route packed words into PV A-fragments with permlane32/16_swap.
      bf16x8 ap[2][2];
#pragma unroll
      for (int mt = 0; mt < 2; ++mt) {
        unsigned pk0, pk1, pk2, pk3, pk4, pk5, pk6, pk7;
        {
          float p0 = __builtin_amdgcn_exp2f(s[mt][0][0]);
          float p1 = __builtin_amdgcn_exp2f(s[mt][0][1]);
          float p2 = __builtin_amdgcn_exp2f(s[mt][0][2]);
          float p3 = __builtin_amdgcn_exp2f(s[mt][0][3]);
          asm("v_cvt_pk_bf16_f32 %0, %1, %2" : "=v"(pk0) : "v"(p0), "v"(p1));
          asm("v_cvt_pk_bf16_f32 %0, %1, %2" : "=v"(pk1) : "v"(p2), "v"(p3));
        }
        {
          float p0 = __builtin_amdgcn_exp2f(s[mt][1][0]);
          float p1 = __builtin_amdgcn_exp2f(s[mt][1][1]);
          float p2 = __builtin_amdgcn_exp2f(s[mt][1][2]);
          float p3 = __builtin_amdgcn_exp2f(s[mt][1][3]);
          asm("v_cvt_pk_bf16_f32 %0, %1, %2" : "=v"(pk2) : "v"(p0), "v"(p1));
          asm("v_cvt_pk_bf16_f32 %0, %1, %2" : "=v"(pk3) : "v"(p2), "v"(p3));
        }
        {
          float p0 = __builtin_amdgcn_exp2f(s[mt][2][0]);
          float p1 = __builtin_amdgcn_exp2f(s[mt][2][1]);
          float p2 = __builtin_amdgcn_exp2f(s[mt][2][2]);
          float p3 = __builtin_amdgcn_exp2f(s[mt][2][3]);
          asm("v_cvt_pk_bf16_f32 %0, %1, %2" : "=v"(pk4) : "v"(p0), "v"(p1));
          asm("v_cvt_pk_bf16_f32 %0, %1, %2" : "=v"(pk5) : "v"(p2), "v"(p3));
        }
        {
          float p0 = __builtin_amdgcn_exp2f(s[mt][3][0]);
          float p1 = __builtin_amdgcn_exp2f(s[mt][3][1]);
          float p2 = __builtin_amdgcn_exp2f(s[mt][3][2]);
          float p3 = __builtin_amdgcn_exp2f(s[mt][3][3]);
          asm("v_cvt_pk_bf16_f32 %0, %1, %2" : "=v"(pk6) : "v"(p0), "v"(p1));
          asm("v_cvt_pk_bf16_f32 %0, %1, %2" : "=v"(pk7) : "v"(p2), "v"(p3));
        }
        {
          unsigned a0 = pk0, b0 = pk2;
          asm("v_permlane32_swap_b32 %0, %1" : "+v"(a0), "+v"(b0));
          asm("v_permlane16_swap_b32 %0, %1" : "+v"(a0), "+v"(b0));
          unsigned a1 = pk1, b1 = pk3;
          asm("v_permlane32_swap_b32 %0, %1" : "+v"(a1), "+v"(b1));
          asm("v_permlane16_swap_b32 %0, %1" : "+v"(a1), "+v"(b1));
          u32x4 w; w.x = a0; w.y = a1; w.z = b0; w.w = b1;
          ap[mt][0] = __builtin_bit_cast(bf16x8, w);
        }
        {
          unsigned a0 = pk4, b0 = pk6;
          asm("v_permlane32_swap_b32 %0, %1" : "+v"(a0), "+v"(b0));
          asm("v_permlane16_swap_b32 %0, %1" : "+v"(a0), "+v"(b0));
          unsigned a1 = pk5, b1 = pk7;
          asm("v_permlane32_swap_b32 %0, %1" : "+v"(a1), "+v"(b1));
          asm("v_permlane16_swap_b32 %0, %1" : "+v"(a1), "+v"(b1));
          u32x4 w; w.x = a0; w.y = a1; w.z = b0; w.w = b1;
          ap[mt][1] = __builtin_bit_cast(bf16x8, w);
        }
      }

      // O += P V ; ell += P 1
#pragma unroll
      for (int ks = 0; ks < 2; ++ks) {
        bf16x8 bv[4];
#pragma unroll
        for (int dt = 0; dt < 4; ++dt) {
          int row  = dt * 16 + l16;
          int slot = (ks * 4 + q4) ^ (row & 7);
          bv[dt] = *(const bf16x8*)&Vs[half][row * 64 + slot * 8];
        }
#pragma unroll
        for (int mt = 0; mt < 2; ++mt) {
#pragma unroll
          for (int dt = 0; dt < 4; ++dt)
            o[mt][dt] = __builtin_amdgcn_mfma_f32_16x16x32_bf16(ap[mt][ks], bv[dt],
                                                                o[mt][dt], 0, 0, 0);
          o_l[mt] = __builtin_amdgcn_mfma_f32_16x16x32_bf16(ap[mt][ks], ones_f,
                                                            o_l[mt], 0, 0, 0);
        }
      }
    }
  }

  // epilogue: normalize (row-sum broadcast from col-0 lane) and store bf16
#pragma unroll
  for (int mt = 0; mt < 2; ++mt) {
    float inv[4];
#pragma unroll
    for (int r = 0; r < 4; ++r) {
      float lsum = __shfl(o_l[mt][r], lane & 48);   // lane q4*16 holds col 0
      inv[r] = 1.0f / lsum;
    }
#pragma unroll
    for (int dt = 0; dt < 4; ++dt)
#pragma unroll
      for (int r = 0; r < 4; ++r) {
        long row = rowbase + wq0 + mt * 16 + q4 * 4 + r;
        int col = h * 64 + dt * 16 + l16;
        outb[row * 2048 + col] = (bf16)(o[mt][dt][r] * inv[r]);
      }
  }
}

// --------------------------------------------------------------------------------
extern "C" void kernel_launch(void* const* d_in, const int* in_sizes, int n_in,
                              void* d_out, int out_size, void* d_ws, size_t ws_size,
                              hipStream_t stream) {
  const float* x   = (const float*)d_in[0];
  const float* wq  = (const float*)d_in[1];
  const float* wkv = (const float*)d_in[2];
  const float* wo  = (const float*)d_in[3];
  float* out = (float*)d_out;
  char* ws = (char*)d_ws;

  // ws layout (bytes):
  //   xbf  [4096*2048] bf16 @ 0          (16,777,216)  -- reused as attn output
  //   w1   [3072*2048] bf16 @ 16777216   (12,582,912)  -- wq^T | wkv^T
  //   qkv  [4096*3072] bf16 @ 29360128   (25,165,824)  -- ends 54,525,952
  //   woT  [2048*2048] bf16 @ 54525952   ( 8,388,608)  -- ends 62,914,560
  //   vT   [2*512*2048] bf16 @ 62914560  ( 4,194,304)  -- ends 67,108,864
  bf16* xbf  = (bf16*)(ws + 0);
  bf16* w1   = (bf16*)(ws + 16777216);
  bf16* qkv  = (bf16*)(ws + 29360128);
  bf16* attn = xbf;              // xbf dead after gemm1

  const bool fused_v  = ws_size >= 67108864u;   // vT slot after woT
  const bool woT_early = ws_size >= 62914560u;

  bf16* woT = woT_early ? (bf16*)(ws + 54525952) : qkv;   // qkv dead after attn
  bf16* vT  = fused_v   ? (bf16*)(ws + 62914560) : w1;    // w1 dead after gemm1

  // fused prep: z=0 cvt(x), z=1 wq^T, z=2 wkv^T, z=3 wo^T (only if early)
  prep_kernel<<<dim3(64, 64, woT_early ? 4 : 3), 256, 0, stream>>>(
      x, xbf, wq, wkv, wo, w1, woT);

  // qkv = [x@wq | x@wkv]; fused path also writes V directly to vT (transposed)
  if (fused_v) {
    gemm_kernel<true, true><<<dim3(24, 32), 256, 0, stream>>>(
        xbf, w1, (void*)qkv, vT, 2048, 3072);
  } else {
    gemm_kernel<true, false><<<dim3(24, 32), 256, 0, stream>>>(
        xbf, w1, (void*)qkv, nullptr, 2048, 3072);
    transpose_v<<<dim3(16, 128), 256, 0, stream>>>(qkv, vT);  // vT = w1 (dead)
  }

  attn_kernel<<<1024, 256, 0, stream>>>(qkv, vT, attn);

  if (!woT_early)
    transpose_cvt<<<dim3(64, 64), 256, 0, stream>>>(wo, woT, 2048, 2048);

  // out = attn @ wo
  gemm_kernel<false, false><<<dim3(16, 32), 256, 0, stream>>>(
      attn, woT, (void*)out, nullptr, 2048, 2048);
}

// Round 10
// 258.181 us; speedup vs baseline: 1.1372x; 1.1372x over previous
//
#include <hip/hip_runtime.h>

using bf16   = __bf16;
using bf16x8 = __attribute__((ext_vector_type(8))) __bf16;
using f32x4  = __attribute__((ext_vector_type(4))) float;
using u32x4  = __attribute__((ext_vector_type(4))) unsigned;

// B=2 T=2048 D=2048 H=32 KVH=8 HD=64 GROUPS=4 ; M=B*T=4096 ; NQKV=3072
#define T_SEQ 2048
#define NQKV 3072

__device__ __forceinline__ void async_cp16(const bf16* g, bf16* l) {
  __builtin_amdgcn_global_load_lds((__attribute__((address_space(1))) void*)(void*)g,
                                   (__attribute__((address_space(3))) void*)l, 16, 0, 0);
}

// ------------- fused prep: cvt(x) | wq^T | wkv^T | wo^T as z-slices -------------
__global__ __launch_bounds__(256) void prep_kernel(
    const float* __restrict__ x, bf16* __restrict__ xbf,
    const float* __restrict__ wq, const float* __restrict__ wkv,
    const float* __restrict__ wo, bf16* __restrict__ w1,
    bf16* __restrict__ woT) {
  const int z = blockIdx.z;
  if (z == 0) {                 // fp32 -> bf16 convert of x (64x64 blocks = 4096)
    long i = (((long)blockIdx.y * 64 + blockIdx.x) * 256 + threadIdx.x) * 8;
    float4 a = *(const float4*)(x + i);
    float4 c = *(const float4*)(x + i + 4);
    bf16x8 v;
    v[0] = (bf16)a.x; v[1] = (bf16)a.y; v[2] = (bf16)a.z; v[3] = (bf16)a.w;
    v[4] = (bf16)c.x; v[5] = (bf16)c.y; v[6] = (bf16)c.z; v[7] = (bf16)c.w;
    *(bf16x8*)(xbf + i) = v;
    return;
  }
  const float* in; bf16* out; int R, C;
  if (z == 1)      { in = wq;  out = w1;                R = 2048; C = 2048; }
  else if (z == 2) { if (blockIdx.x >= 32) return;
                     in = wkv; out = w1 + 2048L * 2048; R = 2048; C = 1024; }
  else             { in = wo;  out = woT;               R = 2048; C = 2048; }
  __shared__ float tile[32][33];
  const int tc = blockIdx.x * 32;
  const int tr = blockIdx.y * 32;
  const int t = threadIdx.x;
  const int lr = t >> 5;
  const int lc = t & 31;
#pragma unroll
  for (int i = 0; i < 4; ++i)
    tile[lr + i * 8][lc] = in[(size_t)(tr + lr + i * 8) * C + tc + lc];
  __syncthreads();
#pragma unroll
  for (int i = 0; i < 4; ++i)
    out[(size_t)(tc + lr + i * 8) * R + tr + lc] = (bf16)tile[lc][lr + i * 8];
}

// ------------- transpose + convert (standalone, fallback paths) ----------------
__global__ __launch_bounds__(256) void transpose_cvt(const float* __restrict__ in,
                                                     bf16* __restrict__ out,
                                                     int R, int C) {
  __shared__ float tile[32][33];
  const int tc = blockIdx.x * 32;
  const int tr = blockIdx.y * 32;
  const int t = threadIdx.x;
  const int lr = t >> 5;
  const int lc = t & 31;
#pragma unroll
  for (int i = 0; i < 4; ++i)
    tile[lr + i * 8][lc] = in[(size_t)(tr + lr + i * 8) * C + tc + lc];
  __syncthreads();
#pragma unroll
  for (int i = 0; i < 4; ++i)
    out[(size_t)(tc + lr + i * 8) * R + tr + lc] = (bf16)tile[lc][lr + i * 8];
}

// ------------- bf16 transpose of the V block of qkv (fallback path) -------------
__global__ __launch_bounds__(256) void transpose_v(const bf16* __restrict__ in,
                                                   bf16* __restrict__ out) {
  __shared__ bf16 tile[32][33];
  const int c0 = blockIdx.x * 32;   // 0..480
  const int r0 = blockIdx.y * 32;   // 0..4064
  const int t = threadIdx.x;
  const int lr = t >> 5;
  const int lc = t & 31;
#pragma unroll
  for (int i = 0; i < 4; ++i)
    tile[lr + i * 8][lc] = in[(size_t)(r0 + lr + i * 8) * NQKV + 2560 + c0 + lc];
  __syncthreads();
#pragma unroll
  for (int i = 0; i < 4; ++i) {
    int c = c0 + lr + i * 8;
    int r = r0 + lc;
    out[(size_t)((r >> 11) * 512 + c) * 2048 + (r & 2047)] = tile[lc][lr + i * 8];
  }
}

// ------------- GEMM: C[M][N] = A[M][K] * Bt[N][K]^T  (bf16 in, fp32 acc) --------
// (unchanged: m97 structure + V_SPLIT epilogue; inside the 245.2us best run.)
template <bool OUT_BF16, bool V_SPLIT>
__global__ __launch_bounds__(256, 4)
void gemm_kernel(const bf16* __restrict__ A, const bf16* __restrict__ Bt,
                 void* __restrict__ Cout, bf16* __restrict__ vTout,
                 int Kdim, int Ndim) {
  __shared__ __attribute__((aligned(16))) bf16 As[128 * 64];
  __shared__ __attribute__((aligned(16))) bf16 Bs[128 * 64];
  const int tid  = threadIdx.x;
  const int lane = tid & 63;
  const int wave = tid >> 6;
  const int l16  = lane & 15;
  const int q4   = lane >> 4;
  const long m0 = (long)blockIdx.y * 128;
  const long n0 = (long)blockIdx.x * 128;
  const int wm = (wave >> 1) * 64;
  const int wn = (wave & 1) * 64;

  f32x4 acc[4][4] = {};

  for (int k0 = 0; k0 < Kdim; k0 += 64) {
    __syncthreads();
#pragma unroll
    for (int rr = 0; rr < 4; ++rr) {
      int ci  = rr * 256 + tid;     // 16B chunk index 0..1023
      int row = ci >> 3;
      int chp = ci & 7;             // swizzled LDS chunk slot
      int ch  = chp ^ (row & 7);    // global chunk
      async_cp16(A + (m0 + row) * (long)Kdim + k0 + ch * 8, &As[ci * 8]);
      async_cp16(Bt + (n0 + row) * (long)Kdim + k0 + ch * 8, &Bs[ci * 8]);
    }
    __syncthreads();
#pragma unroll
    for (int ks = 0; ks < 2; ++ks) {
      bf16x8 af[4], bfr[4];
#pragma unroll
      for (int mt = 0; mt < 4; ++mt) {
        int row = wm + mt * 16 + l16;
        int chp = (ks * 4 + q4) ^ (row & 7);
        af[mt] = *(const bf16x8*)&As[row * 64 + chp * 8];
      }
#pragma unroll
      for (int nt = 0; nt < 4; ++nt) {
        int row = wn + nt * 16 + l16;
        int chp = (ks * 4 + q4) ^ (row & 7);
        bfr[nt] = *(const bf16x8*)&Bs[row * 64 + chp * 8];
      }
#pragma unroll
      for (int mt = 0; mt < 4; ++mt)
#pragma unroll
        for (int nt = 0; nt < 4; ++nt)
          acc[mt][nt] = __builtin_amdgcn_mfma_f32_16x16x32_bf16(af[mt], bfr[nt],
                                                                acc[mt][nt], 0, 0, 0);
    }
  }

  if constexpr (V_SPLIT) {
    if (n0 >= 2560) {   // V block: write transposed directly to vT
#pragma unroll
      for (int mt = 0; mt < 4; ++mt)
#pragma unroll
        for (int nt = 0; nt < 4; ++nt)
#pragma unroll
          for (int r = 0; r < 4; ++r) {
            long row = m0 + wm + mt * 16 + q4 * 4 + r;
            long c   = n0 + wn + nt * 16 + l16 - 2560;
            vTout[((row >> 11) * 512 + c) * 2048 + (row & 2047)] =
                (bf16)acc[mt][nt][r];
          }
      return;
    }
  }
#pragma unroll
  for (int mt = 0; mt < 4; ++mt)
#pragma unroll
    for (int nt = 0; nt < 4; ++nt)
#pragma unroll
      for (int r = 0; r < 4; ++r) {
        long row = m0 + wm + mt * 16 + q4 * 4 + r;
        long col = n0 + wn + nt * 16 + l16;
        float v = acc[mt][nt][r];
        if constexpr (OUT_BF16)
          ((bf16*)Cout)[row * Ndim + col] = (bf16)v;
        else
          ((float*)Cout)[row * Ndim + col] = v;
      }
}

// ------------- causal GQA flash attention ---------------------------------------
// r17 = REVERT to the r14/r8 attn (KVBLK=64, T14 2-reg prefetch - the config
// inside the measured-best 245.2us run). r16's KVBLK=128 spilled: kr[4]/vr[4]
// prefetch + live set blew the (256,3) budget (WRITE_SIZE 16.4 -> 166 MB,
// attn 50 -> 95us). 3/3 pattern: attn live-set growth past the cap = spill.
// Added: T5 s_setprio(1) around MFMA clusters (catalog: +4-7% on attn-like
// structures with phase-staggered co-resident blocks; no reg/layout impact).
__global__ __launch_bounds__(256, 3)
void attn_kernel(const bf16* __restrict__ qkv, const bf16* __restrict__ vT,
                 bf16* __restrict__ outb) {
  __shared__ __attribute__((aligned(16))) bf16 Ks[64 * 64];   // swizzled chunks
  __shared__ __attribute__((aligned(16))) bf16 Vs[64 * 64];   // V^T tile, swizzled

  const int tid  = threadIdx.x;
  const int lane = tid & 63;
  const int wave = tid >> 6;
  const int l16  = lane & 15;
  const int q4   = lane >> 4;

  const int bid = blockIdx.x;
  const int qt  = 15 - (bid >> 6);   // heavy q-tiles dispatched first
  const int bh  = bid & 63;
  const int b   = bh >> 5;
  const int h   = bh & 31;
  const int kvh = h >> 2;
  const long rowbase = (long)b * T_SEQ;

  const int qrow0 = qt * 128;
  const int wq0   = qrow0 + wave * 32;
  const float cexp = 0.125f * 1.4426950408889634f;  // scale * log2(e), folded into Q

  // Q fragments in registers, pre-scaled by cexp (so P = exp2(S) directly)
  bf16x8 aq[2][2];
#pragma unroll
  for (int mt = 0; mt < 2; ++mt)
#pragma unroll
    for (int ks = 0; ks < 2; ++ks) {
      bf16x8 v = *(const bf16x8*)(qkv +
          (rowbase + wq0 + mt * 16 + l16) * (long)NQKV + h * 64 + ks * 32 + q4 * 8);
#pragma unroll
      for (int i = 0; i < 8; ++i) v[i] = (bf16)((float)v[i] * cexp);
      aq[mt][ks] = v;
    }

  // ones B-fragment: B[k][n=0]=1 -> accumulates row-sums of P into col 0
  bf16x8 ones_f;
#pragma unroll
  for (int i = 0; i < 8; ++i) ones_f[i] = (l16 == 0) ? (bf16)1.0f : (bf16)0.0f;

  f32x4 o[2][4] = {};
  f32x4 o_l[2] = {};

  const bf16* kbase = qkv + rowbase * (long)NQKV + 2048 + kvh * 64;
  const bf16* vbase = vT + ((long)b * 512 + kvh * 64) * 2048;

  const int ntiles = (qrow0 + 128) >> 6;

  // T14 prologue: tile 0 -> regs
  bf16x8 kr[2], vr[2];
#pragma unroll
  for (int h2 = 0; h2 < 2; ++h2) {
    int ci = h2 * 256 + tid, row = ci >> 3, ch = (ci & 7) ^ (row & 7);
    kr[h2] = *(const bf16x8*)(kbase + (long)row * NQKV + ch * 8);
    vr[h2] = *(const bf16x8*)(vbase + (long)row * 2048 + ch * 8);
  }

  for (int t = 0; t < ntiles; ++t) {
    const int j0 = t * 64;
    __syncthreads();                     // all waves done reading prev tile's LDS
#pragma unroll
    for (int h2 = 0; h2 < 2; ++h2) {     // regs -> LDS
      int ci = h2 * 256 + tid;
      *(bf16x8*)&Ks[ci * 8] = kr[h2];
      *(bf16x8*)&Vs[ci * 8] = vr[h2];
    }
    __syncthreads();                     // LDS ready
    if (t + 1 < ntiles) {                // issue next tile's loads; land during compute
      const int jn = j0 + 64;
#pragma unroll
      for (int h2 = 0; h2 < 2; ++h2) {
        int ci = h2 * 256 + tid, row = ci >> 3, ch = (ci & 7) ^ (row & 7);
        kr[h2] = *(const bf16x8*)(kbase + (long)(jn + row) * NQKV + ch * 8);
        vr[h2] = *(const bf16x8*)(vbase + (long)row * 2048 + jn + ch * 8);
      }
    }
    if (j0 > wq0 + 31) continue;   // tile entirely above diagonal for this wave

    // S^T = K Q^T  (operand-swapped: tiles [kv = nt][q = mt])
    f32x4 s[2][4] = {};
#pragma unroll
    for (int ks = 0; ks < 2; ++ks) {
      bf16x8 bk[4];
#pragma unroll
      for (int nt = 0; nt < 4; ++nt) {
        int row  = nt * 16 + l16;
        int slot = (ks * 4 + q4) ^ (row & 7);
        bk[nt] = *(const bf16x8*)&Ks[row * 64 + slot * 8];
      }
      __builtin_amdgcn_s_setprio(1);
#pragma unroll
      for (int mt = 0; mt < 2; ++mt)
#pragma unroll
        for (int nt = 0; nt < 4; ++nt)
          s[mt][nt] = __builtin_amdgcn_mfma_f32_16x16x32_bf16(bk[nt], aq[mt][ks],
                                                              s[mt][nt], 0, 0, 0);
      __builtin_amdgcn_s_setprio(0);
    }

    if (j0 + 63 > wq0) {   // diagonal tile: causal mask (S^T: row=kv, col=q)
#pragma unroll
      for (int mt = 0; mt < 2; ++mt)
#pragma unroll
        for (int nt = 0; nt < 4; ++nt)
#pragma unroll
          for (int r = 0; r < 4; ++r) {
            int rg = wq0 + mt * 16 + l16;          // q row
            int cg = j0 + nt * 16 + q4 * 4 + r;    // kv col
            if (cg > rg) s[mt][nt][r] = -__builtin_inff();
          }
    }

    // P = exp2(S^T) via bare v_exp_f32; pack pairs with v_cvt_pk_bf16_f32;
    // route packed words into PV A-fragments with permlane32/16_swap.
    bf16x8 ap[2][2];
#pragma unroll
    for (int mt = 0; mt < 2; ++mt) {
      unsigned pk0, pk1, pk2, pk3, pk4, pk5, pk6, pk7;  // pk[nt][j], named scalars
      {
        float p0 = __builtin_amdgcn_exp2f(s[mt][0][0]);
        float p1 = __builtin_amdgcn_exp2f(s[mt][0][1]);
        float p2 = __builtin_amdgcn_exp2f(s[mt][0][2]);
        float p3 = __builtin_amdgcn_exp2f(s[mt][0][3]);
        asm("v_cvt_pk_bf16_f32 %0, %1, %2" : "=v"(pk0) : "v"(p0), "v"(p1));
        asm("v_cvt_pk_bf16_f32 %0, %1, %2" : "=v"(pk1) : "v"(p2), "v"(p3));
      }
      {
        float p0 = __builtin_amdgcn_exp2f(s[mt][1][0]);
        float p1 = __builtin_amdgcn_exp2f(s[mt][1][1]);
        float p2 = __builtin_amdgcn_exp2f(s[mt][1][2]);
        float p3 = __builtin_amdgcn_exp2f(s[mt][1][3]);
        asm("v_cvt_pk_bf16_f32 %0, %1, %2" : "=v"(pk2) : "v"(p0), "v"(p1));
        asm("v_cvt_pk_bf16_f32 %0, %1, %2" : "=v"(pk3) : "v"(p2), "v"(p3));
      }
      {
        float p0 = __builtin_amdgcn_exp2f(s[mt][2][0]);
        float p1 = __builtin_amdgcn_exp2f(s[mt][2][1]);
        float p2 = __builtin_amdgcn_exp2f(s[mt][2][2]);
        float p3 = __builtin_amdgcn_exp2f(s[mt][2][3]);
        asm("v_cvt_pk_bf16_f32 %0, %1, %2" : "=v"(pk4) : "v"(p0), "v"(p1));
        asm("v_cvt_pk_bf16_f32 %0, %1, %2" : "=v"(pk5) : "v"(p2), "v"(p3));
      }
      {
        float p0 = __builtin_amdgcn_exp2f(s[mt][3][0]);
        float p1 = __builtin_amdgcn_exp2f(s[mt][3][1]);
        float p2 = __builtin_amdgcn_exp2f(s[mt][3][2]);
        float p3 = __builtin_amdgcn_exp2f(s[mt][3][3]);
        asm("v_cvt_pk_bf16_f32 %0, %1, %2" : "=v"(pk6) : "v"(p0), "v"(p1));
        asm("v_cvt_pk_bf16_f32 %0, %1, %2" : "=v"(pk7) : "v"(p2), "v"(p3));
      }
      // ks = 0: sources pk[0][*], pk[1][*]
      {
        unsigned a0 = pk0, b0 = pk2;
        asm("v_permlane32_swap_b32 %0, %1" : "+v"(a0), "+v"(b0));
        asm("v_permlane16_swap_b32 %0, %1" : "+v"(a0), "+v"(b0));
        unsigned a1 = pk1, b1 = pk3;
        asm("v_permlane32_swap_b32 %0, %1" : "+v"(a1), "+v"(b1));
        asm("v_permlane16_swap_b32 %0, %1" : "+v"(a1), "+v"(b1));
        u32x4 w; w.x = a0; w.y = a1; w.z = b0; w.w = b1;
        ap[mt][0] = __builtin_bit_cast(bf16x8, w);
      }
      // ks = 1: sources pk[2][*], pk[3][*]
      {
        unsigned a0 = pk4, b0 = pk6;
        asm("v_permlane32_swap_b32 %0, %1" : "+v"(a0), "+v"(b0));
        asm("v_permlane16_swap_b32 %0, %1" : "+v"(a0), "+v"(b0));
        unsigned a1 = pk5, b1 = pk7;
        asm("v_permlane32_swap_b32 %0, %1" : "+v"(a1), "+v"(b1));
        asm("v_permlane16_swap_b32 %0, %1" : "+v"(a1), "+v"(b1));
        u32x4 w; w.x = a0; w.y = a1; w.z = b0; w.w = b1;
        ap[mt][1] = __builtin_bit_cast(bf16x8, w);
      }
    }

    // O += P V ; ell += P 1
#pragma unroll
    for (int ks = 0; ks < 2; ++ks) {
      bf16x8 bv[4];
#pragma unroll
      for (int dt = 0; dt < 4; ++dt) {
        int row  = dt * 16 + l16;
        int slot = (ks * 4 + q4) ^ (row & 7);
        bv[dt] = *(const bf16x8*)&Vs[row * 64 + slot * 8];
      }
      __builtin_amdgcn_s_setprio(1);
#pragma unroll
      for (int mt = 0; mt < 2; ++mt) {
#pragma unroll
        for (int dt = 0; dt < 4; ++dt)
          o[mt][dt] = __builtin_amdgcn_mfma_f32_16x16x32_bf16(ap[mt][ks], bv[dt],
                                                              o[mt][dt], 0, 0, 0);
        o_l[mt] = __builtin_amdgcn_mfma_f32_16x16x32_bf16(ap[mt][ks], ones_f,
                                                          o_l[mt], 0, 0, 0);
      }
      __builtin_amdgcn_s_setprio(0);
    }
  }

  // epilogue: normalize (row-sum broadcast from col-0 lane) and store bf16
#pragma unroll
  for (int mt = 0; mt < 2; ++mt) {
    float inv[4];
#pragma unroll
    for (int r = 0; r < 4; ++r) {
      float lsum = __shfl(o_l[mt][r], lane & 48);   // lane q4*16 holds col 0
      inv[r] = 1.0f / lsum;
    }
#pragma unroll
    for (int dt = 0; dt < 4; ++dt)
#pragma unroll
      for (int r = 0; r < 4; ++r) {
        long row = rowbase + wq0 + mt * 16 + q4 * 4 + r;
        int col = h * 64 + dt * 16 + l16;
        outb[row * 2048 + col] = (bf16)(o[mt][dt][r] * inv[r]);
      }
  }
}

// --------------------------------------------------------------------------------
extern "C" void kernel_launch(void* const* d_in, const int* in_sizes, int n_in,
                              void* d_out, int out_size, void* d_ws, size_t ws_size,
                              hipStream_t stream) {
  const float* x   = (const float*)d_in[0];
  const float* wq  = (const float*)d_in[1];
  const float* wkv = (const float*)d_in[2];
  const float* wo  = (const float*)d_in[3];
  float* out = (float*)d_out;
  char* ws = (char*)d_ws;

  // ws layout (bytes):
  //   xbf  [4096*2048] bf16 @ 0          (16,777,216)  -- reused as attn output
  //   w1   [3072*2048] bf16 @ 16777216   (12,582,912)  -- wq^T | wkv^T
  //   qkv  [4096*3072] bf16 @ 29360128   (25,165,824)  -- ends 54,525,952
  //   woT  [2048*2048] bf16 @ 54525952   ( 8,388,608)  -- ends 62,914,560
  //   vT   [2*512*2048] bf16 @ 62914560  ( 4,194,304)  -- ends 67,108,864
  bf16* xbf  = (bf16*)(ws + 0);
  bf16* w1   = (bf16*)(ws + 16777216);
  bf16* qkv  = (bf16*)(ws + 29360128);
  bf16* attn = xbf;              // xbf dead after gemm1

  const bool fused_v  = ws_size >= 67108864u;   // vT slot after woT
  const bool woT_early = ws_size >= 62914560u;

  bf16* woT = woT_early ? (bf16*)(ws + 54525952) : qkv;   // qkv dead after attn
  bf16* vT  = fused_v   ? (bf16*)(ws + 62914560) : w1;    // w1 dead after gemm1

  // fused prep: z=0 cvt(x), z=1 wq^T, z=2 wkv^T, z=3 wo^T (only if early)
  prep_kernel<<<dim3(64, 64, woT_early ? 4 : 3), 256, 0, stream>>>(
      x, xbf, wq, wkv, wo, w1, woT);

  // qkv = [x@wq | x@wkv]; fused path also writes V directly to vT (transposed)
  if (fused_v) {
    gemm_kernel<true, true><<<dim3(24, 32), 256, 0, stream>>>(
        xbf, w1, (void*)qkv, vT, 2048, 3072);
  } else {
    gemm_kernel<true, false><<<dim3(24, 32), 256, 0, stream>>>(
        xbf, w1, (void*)qkv, nullptr, 2048, 3072);
    transpose_v<<<dim3(16, 128), 256, 0, stream>>>(qkv, vT);  // vT = w1 (dead)
  }

  attn_kernel<<<1024, 256, 0, stream>>>(qkv, vT, attn);

  if (!woT_early)
    transpose_cvt<<<dim3(64, 64), 256, 0, stream>>>(wo, woT, 2048, 2048);

  // out = attn @ wo
  gemm_kernel<false, false><<<dim3(16, 32), 256, 0, stream>>>(
      attn, woT, (void*)out, nullptr, 2048, 2048);
}

// Round 11
// 253.533 us; speedup vs baseline: 1.1581x; 1.0183x over previous
//
#include <hip/hip_runtime.h>

using bf16   = __bf16;
using bf16x8 = __attribute__((ext_vector_type(8))) __bf16;
using f32x4  = __attribute__((ext_vector_type(4))) float;
using u32x4  = __attribute__((ext_vector_type(4))) unsigned;

// B=2 T=2048 D=2048 H=32 KVH=8 HD=64 GROUPS=4 ; M=B*T=4096 ; NQKV=3072
#define T_SEQ 2048
#define NQKV 3072

__device__ __forceinline__ void async_cp16(const bf16* g, bf16* l) {
  __builtin_amdgcn_global_load_lds((__attribute__((address_space(1))) void*)(void*)g,
                                   (__attribute__((address_space(3))) void*)l, 16, 0, 0);
}

// ------------- fused prep: cvt(x) | wq^T | wkv^T | wo^T as z-slices -------------
__global__ __launch_bounds__(256) void prep_kernel(
    const float* __restrict__ x, bf16* __restrict__ xbf,
    const float* __restrict__ wq, const float* __restrict__ wkv,
    const float* __restrict__ wo, bf16* __restrict__ w1,
    bf16* __restrict__ woT) {
  const int z = blockIdx.z;
  if (z == 0) {                 // fp32 -> bf16 convert of x (64x64 blocks = 4096)
    long i = (((long)blockIdx.y * 64 + blockIdx.x) * 256 + threadIdx.x) * 8;
    float4 a = *(const float4*)(x + i);
    float4 c = *(const float4*)(x + i + 4);
    bf16x8 v;
    v[0] = (bf16)a.x; v[1] = (bf16)a.y; v[2] = (bf16)a.z; v[3] = (bf16)a.w;
    v[4] = (bf16)c.x; v[5] = (bf16)c.y; v[6] = (bf16)c.z; v[7] = (bf16)c.w;
    *(bf16x8*)(xbf + i) = v;
    return;
  }
  const float* in; bf16* out; int R, C;
  if (z == 1)      { in = wq;  out = w1;                R = 2048; C = 2048; }
  else if (z == 2) { if (blockIdx.x >= 32) return;
                     in = wkv; out = w1 + 2048L * 2048; R = 2048; C = 1024; }
  else             { in = wo;  out = woT;               R = 2048; C = 2048; }
  __shared__ float tile[32][33];
  const int tc = blockIdx.x * 32;
  const int tr = blockIdx.y * 32;
  const int t = threadIdx.x;
  const int lr = t >> 5;
  const int lc = t & 31;
#pragma unroll
  for (int i = 0; i < 4; ++i)
    tile[lr + i * 8][lc] = in[(size_t)(tr + lr + i * 8) * C + tc + lc];
  __syncthreads();
#pragma unroll
  for (int i = 0; i < 4; ++i)
    out[(size_t)(tc + lr + i * 8) * R + tr + lc] = (bf16)tile[lc][lr + i * 8];
}

// ------------- transpose + convert (standalone, fallback paths) ----------------
__global__ __launch_bounds__(256) void transpose_cvt(const float* __restrict__ in,
                                                     bf16* __restrict__ out,
                                                     int R, int C) {
  __shared__ float tile[32][33];
  const int tc = blockIdx.x * 32;
  const int tr = blockIdx.y * 32;
  const int t = threadIdx.x;
  const int lr = t >> 5;
  const int lc = t & 31;
#pragma unroll
  for (int i = 0; i < 4; ++i)
    tile[lr + i * 8][lc] = in[(size_t)(tr + lr + i * 8) * C + tc + lc];
  __syncthreads();
#pragma unroll
  for (int i = 0; i < 4; ++i)
    out[(size_t)(tc + lr + i * 8) * R + tr + lc] = (bf16)tile[lc][lr + i * 8];
}

// ------------- bf16 transpose of the V block of qkv (fallback path) -------------
__global__ __launch_bounds__(256) void transpose_v(const bf16* __restrict__ in,
                                                   bf16* __restrict__ out) {
  __shared__ bf16 tile[32][33];
  const int c0 = blockIdx.x * 32;   // 0..480
  const int r0 = blockIdx.y * 32;   // 0..4064
  const int t = threadIdx.x;
  const int lr = t >> 5;
  const int lc = t & 31;
#pragma unroll
  for (int i = 0; i < 4; ++i)
    tile[lr + i * 8][lc] = in[(size_t)(r0 + lr + i * 8) * NQKV + 2560 + c0 + lc];
  __syncthreads();
#pragma unroll
  for (int i = 0; i < 4; ++i) {
    int c = c0 + lr + i * 8;
    int r = r0 + lc;
    out[(size_t)((r >> 11) * 512 + c) * 2048 + (r & 2047)] = tile[lc][lr + i * 8];
  }
}

// ------------- GEMM: C[M][N] = A[M][K] * Bt[N][K]^T  (bf16 in, fp32 acc) --------
// r18: + T1 XCD-aware block swizzle. FETCH_SIZE 73MB vs ~29MB unique input =
// 2.5x HBM over-fetch: x-fastest dispatch round-robins the 24 n-tiles sharing
// one A-panel across 8 XCD L2s, thrashing each 4MB L2. Swizzle gives each XCD
// a CONTIGUOUS run of nwg/8 tiles (768%8==0, 256%8==0 -> bijective). Pure
// blockIdx remap - correctness-neutral. Verify via FETCH_SIZE drop.
template <bool OUT_BF16, bool V_SPLIT>
__global__ __launch_bounds__(256, 4)
void gemm_kernel(const bf16* __restrict__ A, const bf16* __restrict__ Bt,
                 void* __restrict__ Cout, bf16* __restrict__ vTout,
                 int Kdim, int Ndim) {
  __shared__ __attribute__((aligned(16))) bf16 As[128 * 64];
  __shared__ __attribute__((aligned(16))) bf16 Bs[128 * 64];
  const int tid  = threadIdx.x;
  const int lane = tid & 63;
  const int wave = tid >> 6;
  const int l16  = lane & 15;
  const int q4   = lane >> 4;

  // XCD swizzle: consecutive dispatch ids round-robin XCDs; remap so each XCD
  // owns a contiguous tile range.
  const int nwg = gridDim.x * gridDim.y;
  int wg = blockIdx.y * gridDim.x + blockIdx.x;
  if ((nwg & 7) == 0) wg = (wg & 7) * (nwg >> 3) + (wg >> 3);
  const long m0 = (long)(wg / gridDim.x) * 128;
  const long n0 = (long)(wg % gridDim.x) * 128;

  const int wm = (wave >> 1) * 64;
  const int wn = (wave & 1) * 64;

  f32x4 acc[4][4] = {};

  for (int k0 = 0; k0 < Kdim; k0 += 64) {
    __syncthreads();
#pragma unroll
    for (int rr = 0; rr < 4; ++rr) {
      int ci  = rr * 256 + tid;     // 16B chunk index 0..1023
      int row = ci >> 3;
      int chp = ci & 7;             // swizzled LDS chunk slot
      int ch  = chp ^ (row & 7);    // global chunk
      async_cp16(A + (m0 + row) * (long)Kdim + k0 + ch * 8, &As[ci * 8]);
      async_cp16(Bt + (n0 + row) * (long)Kdim + k0 + ch * 8, &Bs[ci * 8]);
    }
    __syncthreads();
#pragma unroll
    for (int ks = 0; ks < 2; ++ks) {
      bf16x8 af[4], bfr[4];
#pragma unroll
      for (int mt = 0; mt < 4; ++mt) {
        int row = wm + mt * 16 + l16;
        int chp = (ks * 4 + q4) ^ (row & 7);
        af[mt] = *(const bf16x8*)&As[row * 64 + chp * 8];
      }
#pragma unroll
      for (int nt = 0; nt < 4; ++nt) {
        int row = wn + nt * 16 + l16;
        int chp = (ks * 4 + q4) ^ (row & 7);
        bfr[nt] = *(const bf16x8*)&Bs[row * 64 + chp * 8];
      }
#pragma unroll
      for (int mt = 0; mt < 4; ++mt)
#pragma unroll
        for (int nt = 0; nt < 4; ++nt)
          acc[mt][nt] = __builtin_amdgcn_mfma_f32_16x16x32_bf16(af[mt], bfr[nt],
                                                                acc[mt][nt], 0, 0, 0);
    }
  }

  if constexpr (V_SPLIT) {
    if (n0 >= 2560) {   // V block: write transposed directly to vT
#pragma unroll
      for (int mt = 0; mt < 4; ++mt)
#pragma unroll
        for (int nt = 0; nt < 4; ++nt)
#pragma unroll
          for (int r = 0; r < 4; ++r) {
            long row = m0 + wm + mt * 16 + q4 * 4 + r;
            long c   = n0 + wn + nt * 16 + l16 - 2560;
            vTout[((row >> 11) * 512 + c) * 2048 + (row & 2047)] =
                (bf16)acc[mt][nt][r];
          }
      return;
    }
  }
#pragma unroll
  for (int mt = 0; mt < 4; ++mt)
#pragma unroll
    for (int nt = 0; nt < 4; ++nt)
#pragma unroll
      for (int r = 0; r < 4; ++r) {
        long row = m0 + wm + mt * 16 + q4 * 4 + r;
        long col = n0 + wn + nt * 16 + l16;
        float v = acc[mt][nt][r];
        if constexpr (OUT_BF16)
          ((bf16*)Cout)[row * Ndim + col] = (bf16)v;
        else
          ((float*)Cout)[row * Ndim + col] = v;
      }
}

// ------------- causal GQA flash attention ---------------------------------------
// r18 = exact r8/r14 attn (the 245.2us-best config). setprio REMOVED: r17
// measured -13us total with gemms unchanged-or-faster -> setprio hurt attn.
// Mechanism: our 4 waves/block are barrier-locked (lockstep) - the m190
// null/negative regime, not m191's independent-wave regime. Keep: KVBLK=64,
// T14 2-reg prefetch, operand-swapped QK^T, in-register P transpose
// (cvt_pk + permlane32/16), bare v_exp_f32, (256,3).
__global__ __launch_bounds__(256, 3)
void attn_kernel(const bf16* __restrict__ qkv, const bf16* __restrict__ vT,
                 bf16* __restrict__ outb) {
  __shared__ __attribute__((aligned(16))) bf16 Ks[64 * 64];   // swizzled chunks
  __shared__ __attribute__((aligned(16))) bf16 Vs[64 * 64];   // V^T tile, swizzled

  const int tid  = threadIdx.x;
  const int lane = tid & 63;
  const int wave = tid >> 6;
  const int l16  = lane & 15;
  const int q4   = lane >> 4;

  const int bid = blockIdx.x;
  const int qt  = 15 - (bid >> 6);   // heavy q-tiles dispatched first
  const int bh  = bid & 63;
  const int b   = bh >> 5;
  const int h   = bh & 31;
  const int kvh = h >> 2;
  const long rowbase = (long)b * T_SEQ;

  const int qrow0 = qt * 128;
  const int wq0   = qrow0 + wave * 32;
  const float cexp = 0.125f * 1.4426950408889634f;  // scale * log2(e), folded into Q

  // Q fragments in registers, pre-scaled by cexp (so P = exp2(S) directly)
  bf16x8 aq[2][2];
#pragma unroll
  for (int mt = 0; mt < 2; ++mt)
#pragma unroll
    for (int ks = 0; ks < 2; ++ks) {
      bf16x8 v = *(const bf16x8*)(qkv +
          (rowbase + wq0 + mt * 16 + l16) * (long)NQKV + h * 64 + ks * 32 + q4 * 8);
#pragma unroll
      for (int i = 0; i < 8; ++i) v[i] = (bf16)((float)v[i] * cexp);
      aq[mt][ks] = v;
    }

  // ones B-fragment: B[k][n=0]=1 -> accumulates row-sums of P into col 0
  bf16x8 ones_f;
#pragma unroll
  for (int i = 0; i < 8; ++i) ones_f[i] = (l16 == 0) ? (bf16)1.0f : (bf16)0.0f;

  f32x4 o[2][4] = {};
  f32x4 o_l[2] = {};

  const bf16* kbase = qkv + rowbase * (long)NQKV + 2048 + kvh * 64;
  const bf16* vbase = vT + ((long)b * 512 + kvh * 64) * 2048;

  const int ntiles = (qrow0 + 128) >> 6;

  // T14 prologue: tile 0 -> regs
  bf16x8 kr[2], vr[2];
#pragma unroll
  for (int h2 = 0; h2 < 2; ++h2) {
    int ci = h2 * 256 + tid, row = ci >> 3, ch = (ci & 7) ^ (row & 7);
    kr[h2] = *(const bf16x8*)(kbase + (long)row * NQKV + ch * 8);
    vr[h2] = *(const bf16x8*)(vbase + (long)row * 2048 + ch * 8);
  }

  for (int t = 0; t < ntiles; ++t) {
    const int j0 = t * 64;
    __syncthreads();                     // all waves done reading prev tile's LDS
#pragma unroll
    for (int h2 = 0; h2 < 2; ++h2) {     // regs -> LDS
      int ci = h2 * 256 + tid;
      *(bf16x8*)&Ks[ci * 8] = kr[h2];
      *(bf16x8*)&Vs[ci * 8] = vr[h2];
    }
    __syncthreads();                     // LDS ready
    if (t + 1 < ntiles) {                // issue next tile's loads; land during compute
      const int jn = j0 + 64;
#pragma unroll
      for (int h2 = 0; h2 < 2; ++h2) {
        int ci = h2 * 256 + tid, row = ci >> 3, ch = (ci & 7) ^ (row & 7);
        kr[h2] = *(const bf16x8*)(kbase + (long)(jn + row) * NQKV + ch * 8);
        vr[h2] = *(const bf16x8*)(vbase + (long)row * 2048 + jn + ch * 8);
      }
    }
    if (j0 > wq0 + 31) continue;   // tile entirely above diagonal for this wave

    // S^T = K Q^T  (operand-swapped: tiles [kv = nt][q = mt])
    f32x4 s[2][4] = {};
#pragma unroll
    for (int ks = 0; ks < 2; ++ks) {
      bf16x8 bk[4];
#pragma unroll
      for (int nt = 0; nt < 4; ++nt) {
        int row  = nt * 16 + l16;
        int slot = (ks * 4 + q4) ^ (row & 7);
        bk[nt] = *(const bf16x8*)&Ks[row * 64 + slot * 8];
      }
#pragma unroll
      for (int mt = 0; mt < 2; ++mt)
#pragma unroll
        for (int nt = 0; nt < 4; ++nt)
          s[mt][nt] = __builtin_amdgcn_mfma_f32_16x16x32_bf16(bk[nt], aq[mt][ks],
                                                              s[mt][nt], 0, 0, 0);
    }

    if (j0 + 63 > wq0) {   // diagonal tile: causal mask (S^T: row=kv, col=q)
#pragma unroll
      for (int mt = 0; mt < 2; ++mt)
#pragma unroll
        for (int nt = 0; nt < 4; ++nt)
#pragma unroll
          for (int r = 0; r < 4; ++r) {
            int rg = wq0 + mt * 16 + l16;          // q row
            int cg = j0 + nt * 16 + q4 * 4 + r;    // kv col
            if (cg > rg) s[mt][nt][r] = -__builtin_inff();
          }
    }

    // P = exp2(S^T) via bare v_exp_f32; pack pairs with v_cvt_pk_bf16_f32;
    // route packed words into PV A-fragments with permlane32/16_swap.
    bf16x8 ap[2][2];
#pragma unroll
    for (int mt = 0; mt < 2; ++mt) {
      unsigned pk0, pk1, pk2, pk3, pk4, pk5, pk6, pk7;  // pk[nt][j], named scalars
      {
        float p0 = __builtin_amdgcn_exp2f(s[mt][0][0]);
        float p1 = __builtin_amdgcn_exp2f(s[mt][0][1]);
        float p2 = __builtin_amdgcn_exp2f(s[mt][0][2]);
        float p3 = __builtin_amdgcn_exp2f(s[mt][0][3]);
        asm("v_cvt_pk_bf16_f32 %0, %1, %2" : "=v"(pk0) : "v"(p0), "v"(p1));
        asm("v_cvt_pk_bf16_f32 %0, %1, %2" : "=v"(pk1) : "v"(p2), "v"(p3));
      }
      {
        float p0 = __builtin_amdgcn_exp2f(s[mt][1][0]);
        float p1 = __builtin_amdgcn_exp2f(s[mt][1][1]);
        float p2 = __builtin_amdgcn_exp2f(s[mt][1][2]);
        float p3 = __builtin_amdgcn_exp2f(s[mt][1][3]);
        asm("v_cvt_pk_bf16_f32 %0, %1, %2" : "=v"(pk2) : "v"(p0), "v"(p1));
        asm("v_cvt_pk_bf16_f32 %0, %1, %2" : "=v"(pk3) : "v"(p2), "v"(p3));
      }
      {
        float p0 = __builtin_amdgcn_exp2f(s[mt][2][0]);
        float p1 = __builtin_amdgcn_exp2f(s[mt][2][1]);
        float p2 = __builtin_amdgcn_exp2f(s[mt][2][2]);
        float p3 = __builtin_amdgcn_exp2f(s[mt][2][3]);
        asm("v_cvt_pk_bf16_f32 %0, %1, %2" : "=v"(pk4) : "v"(p0), "v"(p1));
        asm("v_cvt_pk_bf16_f32 %0, %1, %2" : "=v"(pk5) : "v"(p2), "v"(p3));
      }
      {
        float p0 = __builtin_amdgcn_exp2f(s[mt][3][0]);
        float p1 = __builtin_amdgcn_exp2f(s[mt][3][1]);
        float p2 = __builtin_amdgcn_exp2f(s[mt][3][2]);
        float p3 = __builtin_amdgcn_exp2f(s[mt][3][3]);
        asm("v_cvt_pk_bf16_f32 %0, %1, %2" : "=v"(pk6) : "v"(p0), "v"(p1));
        asm("v_cvt_pk_bf16_f32 %0, %1, %2" : "=v"(pk7) : "v"(p2), "v"(p3));
      }
      // ks = 0: sources pk[0][*], pk[1][*]
      {
        unsigned a0 = pk0, b0 = pk2;
        asm("v_permlane32_swap_b32 %0, %1" : "+v"(a0), "+v"(b0));
        asm("v_permlane16_swap_b32 %0, %1" : "+v"(a0), "+v"(b0));
        unsigned a1 = pk1, b1 = pk3;
        asm("v_permlane32_swap_b32 %0, %1" : "+v"(a1), "+v"(b1));
        asm("v_permlane16_swap_b32 %0, %1" : "+v"(a1), "+v"(b1));
        u32x4 w; w.x = a0; w.y = a1; w.z = b0; w.w = b1;
        ap[mt][0] = __builtin_bit_cast(bf16x8, w);
      }
      // ks = 1: sources pk[2][*], pk[3][*]
      {
        unsigned a0 = pk4, b0 = pk6;
        asm("v_permlane32_swap_b32 %0, %1" : "+v"(a0), "+v"(b0));
        asm("v_permlane16_swap_b32 %0, %1" : "+v"(a0), "+v"(b0));
        unsigned a1 = pk5, b1 = pk7;
        asm("v_permlane32_swap_b32 %0, %1" : "+v"(a1), "+v"(b1));
        asm("v_permlane16_swap_b32 %0, %1" : "+v"(a1), "+v"(b1));
        u32x4 w; w.x = a0; w.y = a1; w.z = b0; w.w = b1;
        ap[mt][1] = __builtin_bit_cast(bf16x8, w);
      }
    }

    // O += P V ; ell += P 1
#pragma unroll
    for (int ks = 0; ks < 2; ++ks) {
      bf16x8 bv[4];
#pragma unroll
      for (int dt = 0; dt < 4; ++dt) {
        int row  = dt * 16 + l16;
        int slot = (ks * 4 + q4) ^ (row & 7);
        bv[dt] = *(const bf16x8*)&Vs[row * 64 + slot * 8];
      }
#pragma unroll
      for (int mt = 0; mt < 2; ++mt) {
#pragma unroll
        for (int dt = 0; dt < 4; ++dt)
          o[mt][dt] = __builtin_amdgcn_mfma_f32_16x16x32_bf16(ap[mt][ks], bv[dt],
                                                              o[mt][dt], 0, 0, 0);
        o_l[mt] = __builtin_amdgcn_mfma_f32_16x16x32_bf16(ap[mt][ks], ones_f,
                                                          o_l[mt], 0, 0, 0);
      }
    }
  }

  // epilogue: normalize (row-sum broadcast from col-0 lane) and store bf16
#pragma unroll
  for (int mt = 0; mt < 2; ++mt) {
    float inv[4];
#pragma unroll
    for (int r = 0; r < 4; ++r) {
      float lsum = __shfl(o_l[mt][r], lane & 48);   // lane q4*16 holds col 0
      inv[r] = 1.0f / lsum;
    }
#pragma unroll
    for (int dt = 0; dt < 4; ++dt)
#pragma unroll
      for (int r = 0; r < 4; ++r) {
        long row = rowbase + wq0 + mt * 16 + q4 * 4 + r;
        int col = h * 64 + dt * 16 + l16;
        outb[row * 2048 + col] = (bf16)(o[mt][dt][r] * inv[r]);
      }
  }
}

// --------------------------------------------------------------------------------
extern "C" void kernel_launch(void* const* d_in, const int* in_sizes, int n_in,
                              void* d_out, int out_size, void* d_ws, size_t ws_size,
                              hipStream_t stream) {
  const float* x   = (const float*)d_in[0];
  const float* wq  = (const float*)d_in[1];
  const float* wkv = (const float*)d_in[2];
  const float* wo  = (const float*)d_in[3];
  float* out = (float*)d_out;
  char* ws = (char*)d_ws;

  // ws layout (bytes):
  //   xbf  [4096*2048] bf16 @ 0          (16,777,216)  -- reused as attn output
  //   w1   [3072*2048] bf16 @ 16777216   (12,582,912)  -- wq^T | wkv^T
  //   qkv  [4096*3072] bf16 @ 29360128   (25,165,824)  -- ends 54,525,952
  //   woT  [2048*2048] bf16 @ 54525952   ( 8,388,608)  -- ends 62,914,560
  //   vT   [2*512*2048] bf16 @ 62914560  ( 4,194,304)  -- ends 67,108,864
  bf16* xbf  = (bf16*)(ws + 0);
  bf16* w1   = (bf16*)(ws + 16777216);
  bf16* qkv  = (bf16*)(ws + 29360128);
  bf16* attn = xbf;              // xbf dead after gemm1

  const bool fused_v  = ws_size >= 67108864u;   // vT slot after woT
  const bool woT_early = ws_size >= 62914560u;

  bf16* woT = woT_early ? (bf16*)(ws + 54525952) : qkv;   // qkv dead after attn
  bf16* vT  = fused_v   ? (bf16*)(ws + 62914560) : w1;    // w1 dead after gemm1

  // fused prep: z=0 cvt(x), z=1 wq^T, z=2 wkv^T, z=3 wo^T (only if early)
  prep_kernel<<<dim3(64, 64, woT_early ? 4 : 3), 256, 0, stream>>>(
      x, xbf, wq, wkv, wo, w1, woT);

  // qkv = [x@wq | x@wkv]; fused path also writes V directly to vT (transposed)
  if (fused_v) {
    gemm_kernel<true, true><<<dim3(24, 32), 256, 0, stream>>>(
        xbf, w1, (void*)qkv, vT, 2048, 3072);
  } else {
    gemm_kernel<true, false><<<dim3(24, 32), 256, 0, stream>>>(
        xbf, w1, (void*)qkv, nullptr, 2048, 3072);
    transpose_v<<<dim3(16, 128), 256, 0, stream>>>(qkv, vT);  // vT = w1 (dead)
  }

  attn_kernel<<<1024, 256, 0, stream>>>(qkv, vT, attn);

  if (!woT_early)
    transpose_cvt<<<dim3(64, 64), 256, 0, stream>>>(wo, woT, 2048, 2048);

  // out = attn @ wo
  gemm_kernel<false, false><<<dim3(16, 32), 256, 0, stream>>>(
      attn, woT, (void*)out, nullptr, 2048, 2048);
}